// Round 1
// 402.141 us; speedup vs baseline: 1.0095x; 1.0095x over previous
//
#include <hip/hip_runtime.h>
#include <stdint.h>

// Problem constants (fixed by the reference):
#define NB 4
#define NN 50000
#define NE 800000
#define NF 128

#define NBLK 49          // ceil(NN/1024) for the scan
#define LDK 72           // LDS row stride in bf16 elems: 64 K-chunk + 8 pad
#define LDT 136          // epilogue tile row stride (128 + 8 pad)

typedef __attribute__((ext_vector_type(8))) short  bfrag;    // 8 bf16 (4 VGPR)
typedef __attribute__((ext_vector_type(4))) float  ffrag;    // 4 fp32 acc
typedef __attribute__((ext_vector_type(4))) short  short4v;  // 8 B LDS store
typedef __attribute__((ext_vector_type(4))) float  f32x4;    // true vector type for nt stores

// fp32 -> bf16 round-to-nearest-even
__device__ inline unsigned short f2bf(float f) {
    unsigned int u = __builtin_bit_cast(unsigned int, f);
    u += 0x7fffu + ((u >> 16) & 1u);
    return (unsigned short)(u >> 16);
}
__device__ inline float bflo(unsigned int u) { return __builtin_bit_cast(float, u << 16); }
__device__ inline float bfhi(unsigned int u) { return __builtin_bit_cast(float, u & 0xffff0000u); }

// ---------------------------------------------------------------------------
// MFMA GEMM (+fused edge histogram): h[n][b][o] = bf16(sum_f x[m][f]*W[o][f])
// 256 thr = 4 waves; block tile 128x128; wave tile 64x64 (4x4 of 16x16x32).
// ---------------------------------------------------------------------------
__global__ __launch_bounds__(256) void gemm_kernel(
    const float* __restrict__ x,        // [M][NF] fp32
    const float* __restrict__ W,        // [NF][NF] fp32 (row = out feature)
    unsigned short* __restrict__ h,     // [NN][NB][NF] bf16, node-major
    const int* __restrict__ erow,       // fused histogram input
    int* __restrict__ cnt,              // fused histogram output (pre-zeroed)
    int M)
{
    __shared__ short smem[2 * 128 * LDK];   // 36 KiB; reused by epilogue
    short* xs  = smem;
    short* wsh = smem + 128 * LDK;

    const int tid  = threadIdx.x;

    // --- fused histogram (overlaps with GEMM main loop) ---
    for (int e = blockIdx.x * 256 + tid; e < NE; e += gridDim.x * 256)
        atomicAdd(&cnt[erow[e]], 1);

    const int w    = tid >> 6;
    const int lane = tid & 63;
    const int wr   = w >> 1;      // wave row (0..1)
    const int wc   = w & 1;       // wave col (0..1)
    const int q    = lane >> 4;   // quad 0..3
    const int l15  = lane & 15;
    const int m0   = blockIdx.x * 128;

    ffrag acc[4][4];
#pragma unroll
    for (int i = 0; i < 4; ++i)
#pragma unroll
        for (int j = 0; j < 4; ++j) acc[i][j] = (ffrag)0.f;

    for (int kc = 0; kc < 2; ++kc) {
        const int c = kc * 64;
        __syncthreads();
#pragma unroll
        for (int it = 0; it < 8; ++it) {
            int linear = it * 256 + tid;   // 0..2047
            int r  = linear >> 4;          // 0..127
            int k4 = linear & 15;          // float4 index (4 k elems)

            float4 wv = *(const float4*)(W + (size_t)r * NF + c + k4 * 4);
            short4v wsv;
            wsv[0] = (short)f2bf(wv.x); wsv[1] = (short)f2bf(wv.y);
            wsv[2] = (short)f2bf(wv.z); wsv[3] = (short)f2bf(wv.w);
            *(short4v*)&wsh[r * LDK + k4 * 4] = wsv;

            int gr = m0 + r;
            float4 xv = make_float4(0.f, 0.f, 0.f, 0.f);
            if (gr < M) xv = *(const float4*)(x + (size_t)gr * NF + c + k4 * 4);
            short4v xsv;
            xsv[0] = (short)f2bf(xv.x); xsv[1] = (short)f2bf(xv.y);
            xsv[2] = (short)f2bf(xv.z); xsv[3] = (short)f2bf(xv.w);
            *(short4v*)&xs[r * LDK + k4 * 4] = xsv;
        }
        __syncthreads();

#pragma unroll
        for (int ks = 0; ks < 2; ++ks) {
            const int ko = ks * 32 + q * 8;
            bfrag a[4], b[4];
#pragma unroll
            for (int i = 0; i < 4; ++i)
                a[i] = *(const bfrag*)&xs[(wr * 64 + i * 16 + l15) * LDK + ko];
#pragma unroll
            for (int j = 0; j < 4; ++j)
                b[j] = *(const bfrag*)&wsh[(wc * 64 + j * 16 + l15) * LDK + ko];
#pragma unroll
            for (int i = 0; i < 4; ++i)
#pragma unroll
                for (int j = 0; j < 4; ++j)
                    acc[i][j] = __builtin_amdgcn_mfma_f32_16x16x32_bf16(
                        a[i], b[j], acc[i][j], 0, 0, 0);
        }
    }

    // --- epilogue: repack through LDS, then coalesced 16 B stores ---
    __syncthreads();                      // done with xs/wsh
    short* tile = smem;                   // [128][LDT] bf16 (34 KiB)
#pragma unroll
    for (int i = 0; i < 4; ++i)
#pragma unroll
        for (int reg = 0; reg < 4; ++reg) {
            int row = wr * 64 + i * 16 + q * 4 + reg;
#pragma unroll
            for (int j = 0; j < 4; ++j)
                tile[row * LDT + wc * 64 + j * 16 + l15] =
                    (short)f2bf(acc[i][j][reg]);
        }
    __syncthreads();
#pragma unroll
    for (int it = 0; it < 8; ++it) {
        int row = it * 16 + (tid >> 4);
        int m   = m0 + row;
        if (m < M) {
            int n  = m % NN;
            int bb = m / NN;
            uint4 v = *(const uint4*)&tile[row * LDT + (tid & 15) * 8];
            *(uint4*)(h + ((size_t)n * NB + bb) * NF + (tid & 15) * 8) = v;
        }
    }
}

// ---------------------------------------------------------------------------
// CSR build: scan1 (per-1024-block exclusive) -> scan2 (block offsets).
// scan3 is folded into scatter/spmm (they add bsum[r>>10] on the fly).
// ---------------------------------------------------------------------------
__global__ __launch_bounds__(1024) void scan1_kernel(
    const int* __restrict__ cnt, int* __restrict__ rs, int* __restrict__ bsum)
{
    __shared__ int wsum[16];
    const int tid  = threadIdx.x;
    const int lane = tid & 63;
    const int wid  = tid >> 6;
    const int i    = blockIdx.x * 1024 + tid;

    int v = (i < NN) ? cnt[i] : 0;
    int incl = v;
#pragma unroll
    for (int off = 1; off < 64; off <<= 1) {
        int t = __shfl_up(incl, off, 64);
        if (lane >= off) incl += t;
    }
    if (lane == 63) wsum[wid] = incl;
    __syncthreads();
    int woff = 0;
    for (int ww = 0; ww < wid; ++ww) woff += wsum[ww];
    if (i < NN) rs[i] = woff + incl - v;   // exclusive within block
    if (tid == 0) {
        int tot = 0;
        for (int ww = 0; ww < 16; ++ww) tot += wsum[ww];
        bsum[blockIdx.x] = tot;
    }
}

__global__ void scan2_kernel(int* __restrict__ bsum)
{
    int lane = threadIdx.x;   // one wave of 64
    int v = (lane < NBLK) ? bsum[lane] : 0;
    int incl = v;
#pragma unroll
    for (int off = 1; off < 64; off <<= 1) {
        int t = __shfl_up(incl, off, 64);
        if (lane >= off) incl += t;
    }
    if (lane < NBLK) bsum[lane] = incl - v;   // exclusive block offsets
}

__global__ void scatter_kernel(const int* __restrict__ row,
                               const int* __restrict__ col,
                               const float* __restrict__ val,
                               const int* __restrict__ rs,
                               const int* __restrict__ bsum,
                               int* __restrict__ cursor,
                               uint2* __restrict__ cv_s)
{
    int e = blockIdx.x * 256 + threadIdx.x;
    if (e < NE) {
        int r   = row[e];
        int p   = atomicAdd(&cursor[r], 1);
        int dst = rs[r] + bsum[r >> 10] + p;
        uint2 cv;
        cv.x = (unsigned)col[e];
        cv.y = __builtin_bit_cast(unsigned, val[e]);
        cv_s[dst] = cv;                       // single 8 B write per edge
    }
}

// ---------------------------------------------------------------------------
// SpMM v2: wave per output row.
//  * One coalesced cv preload per 64 edges (8 B/lane), then v_readlane
//    broadcast: ~1 VMEM op per edge (was 2, with a cv->gather dep chain).
//  * readfirstlane(r) + readlane(cv) scalarize all bookkeeping and the
//    gather base -> saddr-form global_load_dwordx4.
//  * Trip count padded to x4: out-of-range lanes carry cv=(0,0) so they
//    contribute exactly 0 (gather of h row 0 is L1-hot) -> no tail loop.
//  * Nontemporal out stores / cv loads: don't evict h from L2 (FETCH_SIZE
//    showed 7.4x re-fetch of the 51 MB h array).
// ---------------------------------------------------------------------------
__global__ __launch_bounds__(256) void spmm_kernel(
    const unsigned short* __restrict__ h,   // [NN][NB][NF] bf16
    const int* __restrict__ rs,
    const int* __restrict__ bsum,
    const uint2* __restrict__ cv_s,         // packed (col, val)
    float* __restrict__ out)                // [NB][NN][NF] fp32
{
    const int w    = threadIdx.x >> 6;
    const int lane = threadIdx.x & 63;
    int r = blockIdx.x * 4 + w;
    if (r >= NN) return;
    r = __builtin_amdgcn_readfirstlane(r);  // wave-uniform by construction

    const int s = rs[r] + bsum[r >> 10];
    const int e = (r + 1 == NN) ? NE : rs[r + 1] + bsum[(r + 1) >> 10];
    const int b    = lane >> 4;
    const int loff = b * NF + (lane & 15) * 8;   // element offset within h row

    float acc[8];
#pragma unroll
    for (int k = 0; k < 8; ++k) acc[k] = 0.f;

    for (int base = s; base < e; base += 64) {
        const int n = min(64, e - base);
        // coalesced preload of up to 64 edges; inactive lanes -> (col=0,val=0)
        unsigned long long cvp = 0ull;
        if (lane < n)
            cvp = __builtin_nontemporal_load(
                      (const unsigned long long*)(cv_s + base + lane));
        const int cvx = (int)(unsigned)(cvp & 0xffffffffull);   // col
        const int cvy = (int)(unsigned)(cvp >> 32);             // val bits

        const int n4 = (n + 3) & ~3;   // padded: lanes >= n contribute 0
        for (int i = 0; i < n4; i += 4) {
            const unsigned c0 = (unsigned)__builtin_amdgcn_readlane(cvx, i);
            const unsigned c1 = (unsigned)__builtin_amdgcn_readlane(cvx, i + 1);
            const unsigned c2 = (unsigned)__builtin_amdgcn_readlane(cvx, i + 2);
            const unsigned c3 = (unsigned)__builtin_amdgcn_readlane(cvx, i + 3);
            const uint4 q0 = *(const uint4*)(h + (size_t)c0 * (NB * NF) + loff);
            const uint4 q1 = *(const uint4*)(h + (size_t)c1 * (NB * NF) + loff);
            const uint4 q2 = *(const uint4*)(h + (size_t)c2 * (NB * NF) + loff);
            const uint4 q3 = *(const uint4*)(h + (size_t)c3 * (NB * NF) + loff);
            const float v0 = __builtin_bit_cast(
                float, __builtin_amdgcn_readlane(cvy, i));
            const float v1 = __builtin_bit_cast(
                float, __builtin_amdgcn_readlane(cvy, i + 1));
            const float v2 = __builtin_bit_cast(
                float, __builtin_amdgcn_readlane(cvy, i + 2));
            const float v3 = __builtin_bit_cast(
                float, __builtin_amdgcn_readlane(cvy, i + 3));

            acc[0] += v0 * bflo(q0.x); acc[1] += v0 * bfhi(q0.x);
            acc[2] += v0 * bflo(q0.y); acc[3] += v0 * bfhi(q0.y);
            acc[4] += v0 * bflo(q0.z); acc[5] += v0 * bfhi(q0.z);
            acc[6] += v0 * bflo(q0.w); acc[7] += v0 * bfhi(q0.w);
            acc[0] += v1 * bflo(q1.x); acc[1] += v1 * bfhi(q1.x);
            acc[2] += v1 * bflo(q1.y); acc[3] += v1 * bfhi(q1.y);
            acc[4] += v1 * bflo(q1.z); acc[5] += v1 * bfhi(q1.z);
            acc[6] += v1 * bflo(q1.w); acc[7] += v1 * bfhi(q1.w);
            acc[0] += v2 * bflo(q2.x); acc[1] += v2 * bfhi(q2.x);
            acc[2] += v2 * bflo(q2.y); acc[3] += v2 * bfhi(q2.y);
            acc[4] += v2 * bflo(q2.z); acc[5] += v2 * bfhi(q2.z);
            acc[6] += v2 * bflo(q2.w); acc[7] += v2 * bfhi(q2.w);
            acc[0] += v3 * bflo(q3.x); acc[1] += v3 * bfhi(q3.x);
            acc[2] += v3 * bflo(q3.y); acc[3] += v3 * bfhi(q3.y);
            acc[4] += v3 * bflo(q3.z); acc[5] += v3 * bfhi(q3.z);
            acc[6] += v3 * bflo(q3.w); acc[7] += v3 * bfhi(q3.w);
        }
    }

    float* op = out + ((size_t)b * NN + r) * NF + (lane & 15) * 8;
    f32x4 o0 = {acc[0], acc[1], acc[2], acc[3]};
    f32x4 o1 = {acc[4], acc[5], acc[6], acc[7]};
    __builtin_nontemporal_store(o0, (f32x4*)op);
    __builtin_nontemporal_store(o1, (f32x4*)(op + 4));
}

// ---------------------------------------------------------------------------
extern "C" void kernel_launch(void* const* d_in, const int* in_sizes, int n_in,
                              void* d_out, int out_size, void* d_ws, size_t ws_size,
                              hipStream_t stream)
{
    const float* x    = (const float*)d_in[0];
    const float* W    = (const float*)d_in[1];
    const int*   erow = (const int*)d_in[2];
    const int*   ecol = (const int*)d_in[3];
    const float* ev   = (const float*)d_in[4];
    float*       out  = (float*)d_out;

    char*  ws  = (char*)d_ws;
    size_t off = 0;
    auto alloc = [&](size_t bytes) -> void* {
        void* p = ws + off;
        off += (bytes + 255) & ~(size_t)255;
        return p;
    };
    unsigned short* h = (unsigned short*)alloc((size_t)NN * NB * NF * sizeof(unsigned short)); // 51.2 MB
    int*   rs     = (int*)  alloc((size_t)(NN + 1) * sizeof(int));
    int*   cnt    = (int*)  alloc((size_t)2 * NN * sizeof(int));  // cnt + cursor, contiguous
    int*   cursor = cnt + NN;
    int*   bsum   = (int*)  alloc((size_t)64 * sizeof(int));
    uint2* cv_s   = (uint2*)alloc((size_t)NE * sizeof(uint2));

    hipMemsetAsync(cnt, 0, (size_t)2 * NN * sizeof(int), stream);  // cnt + cursor

    const int M = NB * NN;
    gemm_kernel<<<(M + 127) / 128, 256, 0, stream>>>(x, W, h, erow, cnt, M);

    scan1_kernel<<<NBLK, 1024, 0, stream>>>(cnt, rs, bsum);
    scan2_kernel<<<1, 64, 0, stream>>>(bsum);
    scatter_kernel<<<(NE + 255) / 256, 256, 0, stream>>>(erow, ecol, ev, rs,
                                                         bsum, cursor, cv_s);

    spmm_kernel<<<(NN + 3) / 4, 256, 0, stream>>>(h, rs, bsum, cv_s, out);
}

// Round 3
// 378.513 us; speedup vs baseline: 1.0725x; 1.0624x over previous
//
#include <hip/hip_runtime.h>
#include <stdint.h>

// Problem constants (fixed by the reference):
#define NB 4
#define NN 50000
#define NE 800000
#define NF 128

#define NBLK 49          // ceil(NN/1024) for the scan
#define LDW 136          // W-LDS / epilogue-tile row stride in bf16 (128 + 8 pad)

typedef __attribute__((ext_vector_type(8))) short  bfrag;    // 8 bf16 (4 VGPR)
typedef __attribute__((ext_vector_type(4))) float  ffrag;    // 4 fp32 acc
typedef __attribute__((ext_vector_type(4))) short  short4v;  // 8 B LDS store
typedef __attribute__((ext_vector_type(4))) float  f32x4;

// fp32 -> bf16 round-to-nearest-even
__device__ inline unsigned short f2bf(float f) {
    unsigned int u = __builtin_bit_cast(unsigned int, f);
    u += 0x7fffu + ((u >> 16) & 1u);
    return (unsigned short)(u >> 16);
}
__device__ inline float bflo(unsigned int u) { return __builtin_bit_cast(float, u << 16); }
__device__ inline float bfhi(unsigned int u) { return __builtin_bit_cast(float, u & 0xffff0000u); }

// ---------------------------------------------------------------------------
// GEMM v2 (+fused edge histogram): h[n][b][o] = bf16(sum_f x[m][f]*W[o][f])
//
// W (one 64 KB matrix shared by ALL blocks) is staged to LDS as bf16 ONCE
// per block behind a single barrier.  x is never staged: each wave owns a
// 32-row strip and loads its A-fragments straight from global memory
// (per-lane 32 B contiguous), converts in-register, and feeds MFMA.  The
// K-loop contains no __syncthreads, so global x loads pipeline across
// K-chunks and the kernel streams x at HBM rate instead of serializing
// {stage, barrier, MFMA, barrier}.
// Block: 256 thr = 4 waves; block tile 128 rows x 128 feats;
// wave tile 32x128 = 2x8 frags of 16x16x32.
// ---------------------------------------------------------------------------
__global__ __launch_bounds__(256) void gemm_kernel(
    const float* __restrict__ x,        // [M][NF] fp32
    const float* __restrict__ W,        // [NF][NF] fp32 (row = out feature)
    unsigned short* __restrict__ h,     // [NN][NB][NF] bf16, node-major
    const int* __restrict__ erow,       // fused histogram input
    int* __restrict__ cnt,              // fused histogram output (pre-zeroed)
    int M)
{
    __shared__ short wsh[128 * LDW];    // 34.8 KB: W bf16, then epilogue tile

    const int tid = threadIdx.x;

    // --- fused histogram (overlaps with W staging + first x loads) ---
    for (int e = blockIdx.x * 256 + tid; e < NE; e += gridDim.x * 256)
        atomicAdd(&cnt[erow[e]], 1);

    // --- stage W -> LDS bf16, once ---
#pragma unroll
    for (int it = 0; it < 16; ++it) {
        int idx = it * 256 + tid;       // float4 slot 0..4095
        int r   = idx >> 5;             // 0..127
        int c4  = idx & 31;
        float4 wv = *(const float4*)(W + (size_t)r * NF + c4 * 4);
        short4v wsv;
        wsv[0] = (short)f2bf(wv.x); wsv[1] = (short)f2bf(wv.y);
        wsv[2] = (short)f2bf(wv.z); wsv[3] = (short)f2bf(wv.w);
        *(short4v*)&wsh[r * LDW + c4 * 4] = wsv;
    }
    __syncthreads();

    const int w    = tid >> 6;
    const int lane = tid & 63;
    const int q    = lane >> 4;     // 0..3
    const int l15  = lane & 15;
    const int r0   = blockIdx.x * 128 + w * 32;

    // Clamped per-fragment x row pointers (clamp is safe: MFMA rows are
    // independent and out-of-range rows are never stored).
    const float* xp[2];
#pragma unroll
    for (int i = 0; i < 2; ++i) {
        int gr = r0 + i * 16 + l15;
        gr = gr < M ? gr : M - 1;
        xp[i] = x + (size_t)gr * NF + q * 8;
    }

    ffrag acc[2][8];
#pragma unroll
    for (int i = 0; i < 2; ++i)
#pragma unroll
        for (int j = 0; j < 8; ++j) acc[i][j] = (ffrag)0.f;

#pragma unroll 2
    for (int kc = 0; kc < 4; ++kc) {    // K-chunks of 32; NO barriers inside
        bfrag a[2];
#pragma unroll
        for (int i = 0; i < 2; ++i) {
            float4 u0 = *(const float4*)(xp[i] + kc * 32);
            float4 u1 = *(const float4*)(xp[i] + kc * 32 + 4);
            bfrag t;
            t[0] = (short)f2bf(u0.x); t[1] = (short)f2bf(u0.y);
            t[2] = (short)f2bf(u0.z); t[3] = (short)f2bf(u0.w);
            t[4] = (short)f2bf(u1.x); t[5] = (short)f2bf(u1.y);
            t[6] = (short)f2bf(u1.z); t[7] = (short)f2bf(u1.w);
            a[i] = t;
        }
#pragma unroll
        for (int j = 0; j < 8; ++j) {
            bfrag b = *(const bfrag*)&wsh[(j * 16 + l15) * LDW + kc * 32 + q * 8];
            acc[0][j] = __builtin_amdgcn_mfma_f32_16x16x32_bf16(
                a[0], b, acc[0][j], 0, 0, 0);
            acc[1][j] = __builtin_amdgcn_mfma_f32_16x16x32_bf16(
                a[1], b, acc[1][j], 0, 0, 0);
        }
    }

    // --- epilogue: repack through LDS (reuses wsh), coalesced 16 B stores ---
    __syncthreads();                    // all waves done reading W
    short* tile = wsh;                  // [128][LDW] bf16
#pragma unroll
    for (int i = 0; i < 2; ++i)
#pragma unroll
        for (int reg = 0; reg < 4; ++reg) {
            int row = w * 32 + i * 16 + q * 4 + reg;
#pragma unroll
            for (int j = 0; j < 8; ++j)
                tile[row * LDW + j * 16 + l15] = (short)f2bf(acc[i][j][reg]);
        }
    __syncthreads();
#pragma unroll
    for (int it = 0; it < 8; ++it) {
        int row = it * 16 + (tid >> 4);
        int m   = blockIdx.x * 128 + row;
        if (m < M) {
            int n  = m % NN;
            int bb = m / NN;
            uint4 v = *(const uint4*)&tile[row * LDW + (tid & 15) * 8];
            *(uint4*)(h + ((size_t)n * NB + bb) * NF + (tid & 15) * 8) = v;
        }
    }
}

// ---------------------------------------------------------------------------
// CSR build: scan1 (per-1024-block exclusive) -> scan2 (block offsets).
// scan3 is folded into scatter/spmm (they add bsum[r>>10] on the fly).
// ---------------------------------------------------------------------------
__global__ __launch_bounds__(1024) void scan1_kernel(
    const int* __restrict__ cnt, int* __restrict__ rs, int* __restrict__ bsum)
{
    __shared__ int wsum[16];
    const int tid  = threadIdx.x;
    const int lane = tid & 63;
    const int wid  = tid >> 6;
    const int i    = blockIdx.x * 1024 + tid;

    int v = (i < NN) ? cnt[i] : 0;
    int incl = v;
#pragma unroll
    for (int off = 1; off < 64; off <<= 1) {
        int t = __shfl_up(incl, off, 64);
        if (lane >= off) incl += t;
    }
    if (lane == 63) wsum[wid] = incl;
    __syncthreads();
    int woff = 0;
    for (int ww = 0; ww < wid; ++ww) woff += wsum[ww];
    if (i < NN) rs[i] = woff + incl - v;   // exclusive within block
    if (tid == 0) {
        int tot = 0;
        for (int ww = 0; ww < 16; ++ww) tot += wsum[ww];
        bsum[blockIdx.x] = tot;
    }
}

__global__ void scan2_kernel(int* __restrict__ bsum)
{
    int lane = threadIdx.x;   // one wave of 64
    int v = (lane < NBLK) ? bsum[lane] : 0;
    int incl = v;
#pragma unroll
    for (int off = 1; off < 64; off <<= 1) {
        int t = __shfl_up(incl, off, 64);
        if (lane >= off) incl += t;
    }
    if (lane < NBLK) bsum[lane] = incl - v;   // exclusive block offsets
}

__global__ void scatter_kernel(const int* __restrict__ row,
                               const int* __restrict__ col,
                               const float* __restrict__ val,
                               const int* __restrict__ rs,
                               const int* __restrict__ bsum,
                               int* __restrict__ cursor,
                               uint2* __restrict__ cv_s)
{
    int e = blockIdx.x * 256 + threadIdx.x;
    if (e < NE) {
        int r   = row[e];
        int p   = atomicAdd(&cursor[r], 1);
        int dst = rs[r] + bsum[r >> 10] + p;
        uint2 cv;
        cv.x = (unsigned)col[e];
        cv.y = __builtin_bit_cast(unsigned, val[e]);
        cv_s[dst] = cv;                       // single 8 B write per edge
    }
}

// ---------------------------------------------------------------------------
// SpMM: wave per output row; coalesced cv preload + readlane broadcast
// (1 VMEM op/edge, scalarized bookkeeping).  Measured memory-system-bound
// at ~4 TB/s on the random-gather path; structure-neutral at this point.
// ---------------------------------------------------------------------------
__global__ __launch_bounds__(256) void spmm_kernel(
    const unsigned short* __restrict__ h,   // [NN][NB][NF] bf16
    const int* __restrict__ rs,
    const int* __restrict__ bsum,
    const uint2* __restrict__ cv_s,         // packed (col, val)
    float* __restrict__ out)                // [NB][NN][NF] fp32
{
    const int w    = threadIdx.x >> 6;
    const int lane = threadIdx.x & 63;
    int r = blockIdx.x * 4 + w;
    if (r >= NN) return;
    r = __builtin_amdgcn_readfirstlane(r);  // wave-uniform by construction

    const int s = rs[r] + bsum[r >> 10];
    const int e = (r + 1 == NN) ? NE : rs[r + 1] + bsum[(r + 1) >> 10];
    const int b    = lane >> 4;
    const int loff = b * NF + (lane & 15) * 8;   // element offset within h row

    float acc[8];
#pragma unroll
    for (int k = 0; k < 8; ++k) acc[k] = 0.f;

    for (int base = s; base < e; base += 64) {
        const int n = min(64, e - base);
        // coalesced preload of up to 64 edges; inactive lanes -> (col=0,val=0)
        unsigned long long cvp = 0ull;
        if (lane < n)
            cvp = __builtin_nontemporal_load(
                      (const unsigned long long*)(cv_s + base + lane));
        const int cvx = (int)(unsigned)(cvp & 0xffffffffull);   // col
        const int cvy = (int)(unsigned)(cvp >> 32);             // val bits

        const int n4 = (n + 3) & ~3;   // padded: lanes >= n contribute 0
        for (int i = 0; i < n4; i += 4) {
            const unsigned c0 = (unsigned)__builtin_amdgcn_readlane(cvx, i);
            const unsigned c1 = (unsigned)__builtin_amdgcn_readlane(cvx, i + 1);
            const unsigned c2 = (unsigned)__builtin_amdgcn_readlane(cvx, i + 2);
            const unsigned c3 = (unsigned)__builtin_amdgcn_readlane(cvx, i + 3);
            const uint4 q0 = *(const uint4*)(h + (size_t)c0 * (NB * NF) + loff);
            const uint4 q1 = *(const uint4*)(h + (size_t)c1 * (NB * NF) + loff);
            const uint4 q2 = *(const uint4*)(h + (size_t)c2 * (NB * NF) + loff);
            const uint4 q3 = *(const uint4*)(h + (size_t)c3 * (NB * NF) + loff);
            const float v0 = __builtin_bit_cast(
                float, __builtin_amdgcn_readlane(cvy, i));
            const float v1 = __builtin_bit_cast(
                float, __builtin_amdgcn_readlane(cvy, i + 1));
            const float v2 = __builtin_bit_cast(
                float, __builtin_amdgcn_readlane(cvy, i + 2));
            const float v3 = __builtin_bit_cast(
                float, __builtin_amdgcn_readlane(cvy, i + 3));

            acc[0] += v0 * bflo(q0.x); acc[1] += v0 * bfhi(q0.x);
            acc[2] += v0 * bflo(q0.y); acc[3] += v0 * bfhi(q0.y);
            acc[4] += v0 * bflo(q0.z); acc[5] += v0 * bfhi(q0.z);
            acc[6] += v0 * bflo(q0.w); acc[7] += v0 * bfhi(q0.w);
            acc[0] += v1 * bflo(q1.x); acc[1] += v1 * bfhi(q1.x);
            acc[2] += v1 * bflo(q1.y); acc[3] += v1 * bfhi(q1.y);
            acc[4] += v1 * bflo(q1.z); acc[5] += v1 * bfhi(q1.z);
            acc[6] += v1 * bflo(q1.w); acc[7] += v1 * bfhi(q1.w);
            acc[0] += v2 * bflo(q2.x); acc[1] += v2 * bfhi(q2.x);
            acc[2] += v2 * bflo(q2.y); acc[3] += v2 * bfhi(q2.y);
            acc[4] += v2 * bflo(q2.z); acc[5] += v2 * bfhi(q2.z);
            acc[6] += v2 * bflo(q2.w); acc[7] += v2 * bfhi(q2.w);
            acc[0] += v3 * bflo(q3.x); acc[1] += v3 * bfhi(q3.x);
            acc[2] += v3 * bflo(q3.y); acc[3] += v3 * bfhi(q3.y);
            acc[4] += v3 * bflo(q3.z); acc[5] += v3 * bfhi(q3.z);
            acc[6] += v3 * bflo(q3.w); acc[7] += v3 * bfhi(q3.w);
        }
    }

    float* op = out + ((size_t)b * NN + r) * NF + (lane & 15) * 8;
    *(float4*)op       = make_float4(acc[0], acc[1], acc[2], acc[3]);
    *(float4*)(op + 4) = make_float4(acc[4], acc[5], acc[6], acc[7]);
}

// ---------------------------------------------------------------------------
extern "C" void kernel_launch(void* const* d_in, const int* in_sizes, int n_in,
                              void* d_out, int out_size, void* d_ws, size_t ws_size,
                              hipStream_t stream)
{
    const float* x    = (const float*)d_in[0];
    const float* W    = (const float*)d_in[1];
    const int*   erow = (const int*)d_in[2];
    const int*   ecol = (const int*)d_in[3];
    const float* ev   = (const float*)d_in[4];
    float*       out  = (float*)d_out;

    char*  ws  = (char*)d_ws;
    size_t off = 0;
    auto alloc = [&](size_t bytes) -> void* {
        void* p = ws + off;
        off += (bytes + 255) & ~(size_t)255;
        return p;
    };
    unsigned short* h = (unsigned short*)alloc((size_t)NN * NB * NF * sizeof(unsigned short)); // 51.2 MB
    int*   rs     = (int*)  alloc((size_t)(NN + 1) * sizeof(int));
    int*   cnt    = (int*)  alloc((size_t)2 * NN * sizeof(int));  // cnt + cursor, contiguous
    int*   cursor = cnt + NN;
    int*   bsum   = (int*)  alloc((size_t)64 * sizeof(int));
    uint2* cv_s   = (uint2*)alloc((size_t)NE * sizeof(uint2));

    hipMemsetAsync(cnt, 0, (size_t)2 * NN * sizeof(int), stream);  // cnt + cursor

    const int M = NB * NN;
    gemm_kernel<<<(M + 127) / 128, 256, 0, stream>>>(x, W, h, erow, cnt, M);

    scan1_kernel<<<NBLK, 1024, 0, stream>>>(cnt, rs, bsum);
    scan2_kernel<<<1, 64, 0, stream>>>(bsum);
    scatter_kernel<<<(NE + 255) / 256, 256, 0, stream>>>(erow, ecol, ev, rs,
                                                         bsum, cursor, cv_s);

    spmm_kernel<<<(NN + 3) / 4, 256, 0, stream>>>(h, rs, bsum, cv_s, out);
}